// Round 7
// baseline (433.224 us; speedup 1.0000x reference)
//
#include <hip/hip_runtime.h>

#define BB 32
#define NN 8192
#define EE 256
#define NAA 16
#define NCHUNK 64
#define CHUNK 128   // NN / NCHUNK

typedef float f4 __attribute__((ext_vector_type(4)));  // native vec for nontemporal builtins

// ---- workspace float offsets ----
#define KQ_OFF   0
#define ATT_OFF  256
#define PL_OFF   (ATT_OFF + BB*NN)           // per-(b,chunk) exp-sum
#define PS_OFF   (PL_OFF + BB*NCHUNK)        // per-(b,chunk) weighted row-sum s[256]
#define INDS_OFF (PS_OFF + BB*NCHUNK*EE)     // selected indices (int storage)
#define WSEL_OFF (INDS_OFF + BB*NAA)         // selected weights

// ---- output float offsets (outs, inds, weights, barcode_out) ----
#define OUT_OUTS 0
#define OUT_INDS (BB*NAA*EE)
#define OUT_W    (OUT_INDS + BB*NAA)
#define OUT_BC   (OUT_W + BB*NAA)

// kq[f] = (1/16) * Wk[f,:] . q,  q = barcode @ Wq.
// 16 blocks; each block recomputes q redundantly (Wq is L2-resident after
// block 0's first touch) then covers 16 f-rows of Wk. One launch total.
__global__ __launch_bounds__(256) void prep_qk(
    const float* __restrict__ barcode, const float* __restrict__ Wq,
    const float* __restrict__ Wk, float* __restrict__ ws) {
  int blk = blockIdx.x, t = threadIdx.x;
  __shared__ float qs[EE];
  // phase 1: q[t] = sum_f barcode[f] * Wq[f,t]  (coalesced over t; 4-way ILP)
  float a0 = 0.f, a1 = 0.f, a2 = 0.f, a3 = 0.f;
  #pragma unroll 4
  for (int f = 0; f < EE; f += 4) {
    a0 += barcode[f+0] * Wq[(f+0)*EE + t];
    a1 += barcode[f+1] * Wq[(f+1)*EE + t];
    a2 += barcode[f+2] * Wq[(f+2)*EE + t];
    a3 += barcode[f+3] * Wq[(f+3)*EE + t];
  }
  qs[t] = (a0 + a1) + (a2 + a3);
  __syncthreads();
  // phase 2: 16 threads per f-row, f = blk*16 + (t>>4)
  int fi = t >> 4, p = t & 15;
  int f = blk * 16 + fi;
  const float4* wk4 = (const float4*)(Wk + (size_t)f * EE);
  const float4* q4  = (const float4*)qs;
  float acc = 0.f;
  #pragma unroll
  for (int j = 0; j < 4; ++j) {
    float4 wv = wk4[p + 16 * j], qv = q4[p + 16 * j];
    acc += wv.x * qv.x + wv.y * qv.y + wv.z * qv.z + wv.w * qv.w;
  }
  #pragma unroll
  for (int off = 8; off >= 1; off >>= 1) acc += __shfl_xor(acc, off, 64);
  if (p == 0) ws[KQ_OFF + f] = acc * 0.0625f;
}

// One pass over x: att scores + exp-weighted row-sum partials.
// Quarter-wave layout; nontemporal loads (streamed once, keep LLC clean).
__global__ __launch_bounds__(256) void pass_a(
    const float* __restrict__ x, const float* __restrict__ mask,
    float* __restrict__ ws) {
  const int c = blockIdx.x, b = blockIdx.y;
  const int w = threadIdx.x >> 6, lane = threadIdx.x & 63;
  const int il = lane & 15, q = lane >> 4;
  const float4* kqp = (const float4*)(ws + KQ_OFF);
  const float4 kq0 = kqp[il], kq1 = kqp[il + 16],
               kq2 = kqp[il + 32], kq3 = kqp[il + 48];
  float* att = ws + ATT_OFF + (size_t)b * NN + c * CHUNK;
  const float* xb = x + ((size_t)b * NN + (size_t)c * CHUNK) * EE;
  const float* mb = mask + (size_t)b * NN + c * CHUNK;

  float l = 0.f;
  float4 a0 = {0,0,0,0}, a1 = {0,0,0,0}, a2 = {0,0,0,0}, a3 = {0,0,0,0};
  #pragma unroll
  for (int it = 0; it < 8; ++it) {
    int r = w * 32 + it * 4 + q;             // this group's row
    const f4* xr = (const f4*)(xb + (size_t)r * EE);
    f4 x0 = __builtin_nontemporal_load(xr + il);
    f4 x1 = __builtin_nontemporal_load(xr + il + 16);
    f4 x2 = __builtin_nontemporal_load(xr + il + 32);
    f4 x3 = __builtin_nontemporal_load(xr + il + 48);
    float d = x0.x*kq0.x + x0.y*kq0.y + x0.z*kq0.z + x0.w*kq0.w
            + x1.x*kq1.x + x1.y*kq1.y + x1.z*kq1.z + x1.w*kq1.w
            + x2.x*kq2.x + x2.y*kq2.y + x2.z*kq2.z + x2.w*kq2.w
            + x3.x*kq3.x + x3.y*kq3.y + x3.z*kq3.z + x3.w*kq3.w;
    d += __shfl_xor(d, 8, 64);
    d += __shfl_xor(d, 4, 64);
    d += __shfl_xor(d, 2, 64);
    d += __shfl_xor(d, 1, 64);               // all 16 lanes of group have row dot
    float mk = __builtin_nontemporal_load(mb + r);
    float a = d + ((mk == -2.0f) ? -1e9f : 0.0f);
    if (il == 0) att[r] = a;
    float p = __expf(a) * ((mk == -2.0f) ? 0.f : 1.f);
    l += p;
    a0.x += p*x0.x; a0.y += p*x0.y; a0.z += p*x0.z; a0.w += p*x0.w;
    a1.x += p*x1.x; a1.y += p*x1.y; a1.z += p*x1.z; a1.w += p*x1.w;
    a2.x += p*x2.x; a2.y += p*x2.y; a2.z += p*x2.z; a2.w += p*x2.w;
    a3.x += p*x3.x; a3.y += p*x3.y; a3.z += p*x3.z; a3.w += p*x3.w;
  }
  // fold 16 partials (4 waves x 4 groups), each covering all 256 cols once
  __shared__ float ss[16][EE];
  __shared__ float sl[4];
  int s = w * 4 + q;
  ((float4*)ss[s])[il]      = a0;
  ((float4*)ss[s])[il + 16] = a1;
  ((float4*)ss[s])[il + 32] = a2;
  ((float4*)ss[s])[il + 48] = a3;
  l += __shfl_xor(l, 16, 64);
  l += __shfl_xor(l, 32, 64);                // wave-total exp-sum
  if (lane == 0) sl[w] = l;
  __syncthreads();
  int t = threadIdx.x;
  float S = 0.f;
  #pragma unroll
  for (int si = 0; si < 16; ++si) S += ss[si][t];
  ws[PS_OFF + (size_t)(b * NCHUNK + c) * EE + t] = S;
  if (t == 0) ws[PL_OFF + b * NCHUNK + c] = sl[0] + sl[1] + sl[2] + sl[3];
}

// Fused per-batch (1024 threads): fold chunk partials -> L, S;
// barcode_out = (S/L)@Wv; greedy distance-constrained top-16 on RAW att.
__global__ __launch_bounds__(1024) void combine_select(
    const float* __restrict__ Wv, float* __restrict__ ws, float* __restrict__ out) {
  int b = blockIdx.x, t = threadIdx.x;
  int w16 = t >> 6, lane = t & 63;
  int col = t & 255, q4 = t >> 8;
  __shared__ float sn[EE];
  __shared__ float p[NN];
  __shared__ float part[4][EE];
  __shared__ float wvs[16];
  __shared__ int   wis[16];
  __shared__ int   sel[NAA];
  __shared__ float selw[NAA];
  __shared__ float Lsh;
  // S partials: quarter q4 sums 16 of the 64 chunks (coalesced over col)
  float S = 0.f;
  for (int c = q4; c < NCHUNK; c += 4)
    S += ws[PS_OFF + (size_t)(b * NCHUNK + c) * EE + col];
  part[q4][col] = S;
  // L = sum_c PL[b,c] : wave 0 holds c = lane (NCHUNK==64)
  if (t < 64) {
    float lv = ws[PL_OFF + b * NCHUNK + t];
    #pragma unroll
    for (int off = 32; off >= 1; off >>= 1) lv += __shfl_xor(lv, off, 64);
    if (t == 0) Lsh = lv;
  }
  __syncthreads();
  float L = Lsh;
  if (t < 256) sn[t] = (part[0][t] + part[1][t] + part[2][t] + part[3][t]) / L;
  // load att row into LDS for selection (raw scores; mask already folded in)
  const float* att = ws + ATT_OFF + (size_t)b * NN;
  for (int n = t; n < NN; n += 1024) p[n] = att[n];
  __syncthreads();
  // barcode_out matvec: quarter q4 covers e in [q4*64, q4*64+64)
  {
    float acc = 0.f;
    #pragma unroll 8
    for (int i = 0; i < 64; ++i) {
      int e = q4 * 64 + i;
      acc += sn[e] * Wv[e * EE + col];
    }
    part[q4][col] = acc;   // reuse: prior readers separated by barrier above
  }
  __syncthreads();
  if (t < 256)
    out[OUT_BC + b * EE + t] = part[0][t] + part[1][t] + part[2][t] + part[3][t];
  // greedy top-16, tie -> lowest index (== stable descending argsort scan)
  for (int it = 0; it < NAA; ++it) {
    float v = -INFINITY; int idx = NN;
    #pragma unroll
    for (int k = 0; k < NN / 1024; ++k) {
      int n = t + k * 1024;
      float pv = p[n];
      if (pv > v) { v = pv; idx = n; }                // ascending n -> first max
    }
    #pragma unroll
    for (int off = 32; off >= 1; off >>= 1) {         // wave argmax, tie -> low idx
      float v2 = __shfl_xor(v, off, 64);
      int   i2 = __shfl_xor(idx, off, 64);
      if (v2 > v || (v2 == v && i2 < idx)) { v = v2; idx = i2; }
    }
    if (lane == 0) { wvs[w16] = v; wis[w16] = idx; }
    __syncthreads();
    // redundant parallel merge: every thread computes the same winner
    // (LDS broadcast reads; no wave sits idle behind a wave-0-only phase)
    float bv = wvs[0]; int bi = wis[0];
    #pragma unroll
    for (int j = 1; j < 16; ++j) {
      float v2 = wvs[j]; int i2 = wis[j];
      if (v2 > bv || (v2 == bv && i2 < bi)) { bv = v2; bi = i2; }
    }
    if (t == 0) { sel[it] = bi; selw[it] = bv; }
    int j = bi - 2 + (int)t;                          // threads 0..4 mask winner+/-2
    if (t < 5 && j >= 0 && j <= NN - 1) p[j] = -INFINITY;
    __syncthreads();
  }
  if (t == 0) {  // sort 16 (idx, att) pairs by idx ascending
    for (int i = 1; i < NAA; ++i) {
      int ki = sel[i]; float kw = selw[i]; int j = i - 1;
      while (j >= 0 && sel[j] > ki) { sel[j+1] = sel[j]; selw[j+1] = selw[j]; --j; }
      sel[j+1] = ki; selw[j+1] = kw;
    }
  }
  __syncthreads();
  if (t < NAA) {
    float wt = expf(selw[t]) / L;                     // softmax weight, winners only
    out[OUT_INDS + b * NAA + t] = (float)sel[t];
    out[OUT_W    + b * NAA + t] = wt;
    ((int*)(ws + INDS_OFF))[b * NAA + t] = sel[t];
    ws[WSEL_OFF + b * NAA + t] = wt;
  }
}

// Per (a, 4 b's): w/g tiles loaded once feed 4 rows -> 4x less L2/LLC traffic.
__global__ __launch_bounds__(256) void final_kernel(
    const float* __restrict__ x, const float* __restrict__ g,
    const float* __restrict__ w, const float* __restrict__ ln_gamma,
    const float* __restrict__ ln_beta, const float* __restrict__ ws,
    float* __restrict__ out) {
  int a = blockIdx.x, bg = blockIdx.y, t = threadIdx.x;
  __shared__ float row[4][EE];
  __shared__ float redw[4][4][EE];
  __shared__ float redg[4][4][EE];
  __shared__ float red[4][4];
  float pw = powf(40.0f, (float)t * (1.0f / 256.0f));
  float wts[4];
  #pragma unroll
  for (int rr = 0; rr < 4; ++rr) {
    int b = bg * 4 + rr;
    int ind = ((const int*)(ws + INDS_OFF))[b * NAA + a];
    wts[rr] = ws[WSEL_OFF + b * NAA + a];
    row[rr][t] = x[((size_t)b * NN + ind) * EE + t] + sinf((float)ind / pw);
  }
  __syncthreads();
  int qe = t >> 6, fq = t & 63;
  const float4* wa4 = (const float4*)(w + (size_t)a * EE * EE);
  const float4* ga4 = (const float4*)(g + (size_t)a * EE * EE);
  float4 aw0={0,0,0,0}, aw1={0,0,0,0}, aw2={0,0,0,0}, aw3={0,0,0,0};
  float4 ag0={0,0,0,0}, ag1={0,0,0,0}, ag2={0,0,0,0}, ag3={0,0,0,0};
  #pragma unroll 4
  for (int i = 0; i < 64; ++i) {
    int e = qe * 64 + i;
    float4 wv = wa4[(size_t)e * 64 + fq];
    float4 gv = ga4[(size_t)e * 64 + fq];
    float r0 = row[0][e], r1 = row[1][e], r2 = row[2][e], r3 = row[3][e];
    aw0.x += r0*wv.x; aw0.y += r0*wv.y; aw0.z += r0*wv.z; aw0.w += r0*wv.w;
    aw1.x += r1*wv.x; aw1.y += r1*wv.y; aw1.z += r1*wv.z; aw1.w += r1*wv.w;
    aw2.x += r2*wv.x; aw2.y += r2*wv.y; aw2.z += r2*wv.z; aw2.w += r2*wv.w;
    aw3.x += r3*wv.x; aw3.y += r3*wv.y; aw3.z += r3*wv.z; aw3.w += r3*wv.w;
    ag0.x += r0*gv.x; ag0.y += r0*gv.y; ag0.z += r0*gv.z; ag0.w += r0*gv.w;
    ag1.x += r1*gv.x; ag1.y += r1*gv.y; ag1.z += r1*gv.z; ag1.w += r1*gv.w;
    ag2.x += r2*gv.x; ag2.y += r2*gv.y; ag2.z += r2*gv.z; ag2.w += r2*gv.w;
    ag3.x += r3*gv.x; ag3.y += r3*gv.y; ag3.z += r3*gv.z; ag3.w += r3*gv.w;
  }
  ((float4*)redw[0][qe])[fq] = aw0; ((float4*)redw[1][qe])[fq] = aw1;
  ((float4*)redw[2][qe])[fq] = aw2; ((float4*)redw[3][qe])[fq] = aw3;
  ((float4*)redg[0][qe])[fq] = ag0; ((float4*)redg[1][qe])[fq] = ag1;
  ((float4*)redg[2][qe])[fq] = ag2; ((float4*)redg[3][qe])[fq] = ag3;
  __syncthreads();
  float val[4];
  #pragma unroll
  for (int rr = 0; rr < 4; ++rr) {
    float ow = redw[rr][0][t] + redw[rr][1][t] + redw[rr][2][t] + redw[rr][3][t];
    float og = redg[rr][0][t] + redg[rr][1][t] + redg[rr][2][t] + redg[rr][3][t];
    val[rr] = ow * (1.f / (1.f + expf(-og))) * wts[rr];
  }
  int wv_ = t >> 6, ln = t & 63;
  #pragma unroll
  for (int rr = 0; rr < 4; ++rr) {
    float s = val[rr];
    #pragma unroll
    for (int off = 32; off >= 1; off >>= 1) s += __shfl_xor(s, off, 64);
    if (ln == 0) red[rr][wv_] = s;
  }
  __syncthreads();
  float mu[4], dv[4];
  #pragma unroll
  for (int rr = 0; rr < 4; ++rr)
    mu[rr] = (red[rr][0] + red[rr][1] + red[rr][2] + red[rr][3]) * (1.f/256.f);
  __syncthreads();
  #pragma unroll
  for (int rr = 0; rr < 4; ++rr) {
    dv[rr] = val[rr] - mu[rr];
    float sq = dv[rr] * dv[rr];
    #pragma unroll
    for (int off = 32; off >= 1; off >>= 1) sq += __shfl_xor(sq, off, 64);
    if (ln == 0) red[rr][wv_] = sq;
  }
  __syncthreads();
  #pragma unroll
  for (int rr = 0; rr < 4; ++rr) {
    int b = bg * 4 + rr;
    float var = (red[rr][0] + red[rr][1] + red[rr][2] + red[rr][3]) * (1.f/256.f);
    out[OUT_OUTS + ((size_t)b * NAA + a) * EE + t] =
        dv[rr] * rsqrtf(var + 0.001f) * ln_gamma[t] + ln_beta[t];
  }
}

extern "C" void kernel_launch(void* const* d_in, const int* in_sizes, int n_in,
                              void* d_out, int out_size, void* d_ws, size_t ws_size,
                              hipStream_t stream) {
  const float* x       = (const float*)d_in[0];
  const float* mask    = (const float*)d_in[1];
  const float* barcode = (const float*)d_in[2];
  const float* Wq      = (const float*)d_in[3];
  const float* Wk      = (const float*)d_in[4];
  const float* Wv      = (const float*)d_in[5];
  const float* g       = (const float*)d_in[6];
  const float* w       = (const float*)d_in[7];
  const float* gamma   = (const float*)d_in[8];
  const float* beta    = (const float*)d_in[9];
  float* out = (float*)d_out;
  float* ws  = (float*)d_ws;

  prep_qk<<<16, 256, 0, stream>>>(barcode, Wq, Wk, ws);
  pass_a<<<dim3(NCHUNK, BB), 256, 0, stream>>>(x, mask, ws);
  combine_select<<<BB, 1024, 0, stream>>>(Wv, ws, out);
  final_kernel<<<dim3(NAA, BB/4), 256, 0, stream>>>(x, g, w, gamma, beta, ws, out);
}